// Round 3
// baseline (137.551 us; speedup 1.0000x reference)
//
#include <hip/hip_runtime.h>
#include <hip/hip_bf16.h>
#include <stdint.h>

#define B_  32
#define LC  1024
#define LQ  128
#define DD  1024
#define CT  64
#define BK  64

typedef __attribute__((ext_vector_type(8))) short short8;
typedef __attribute__((ext_vector_type(4))) float f4;
typedef unsigned short u16;

__device__ __forceinline__ u16 f2bf(float f) {
  __hip_bfloat16 h = __float2bfloat16(f);
  return *reinterpret_cast<u16*>(&h);
}

// async global->LDS 16B per lane; lds ptr wave-uniform (HW adds lane*16)
__device__ __forceinline__ void gld16(const u16* g, void* l) {
  __builtin_amdgcn_global_load_lds(
      (const __attribute__((address_space(1))) unsigned int*)g,
      (__attribute__((address_space(3))) unsigned int*)l,
      16, 0, 0);
}

// ---------- k1m: q prep — qw3_bf [b][q][d], qT_bf [b][d][q], qw partials ----------
__global__ __launch_bounds__(256) void k1m(const float* __restrict__ qf,
                                           const float* __restrict__ w,
                                           u16* __restrict__ qw3_bf,
                                           u16* __restrict__ qT_bf,
                                           float* __restrict__ qwpart) {
  __shared__ float w3s[128];
  __shared__ float w2s[128];
  __shared__ __align__(16) u16 ldsq[128][136];
  int blk = blockIdx.x;
  int b = blk >> 3, dt = blk & 7;
  int t = threadIdx.x;
  if (t < 128) { w3s[t] = w[2 * DD + dt * 128 + t]; w2s[t] = w[DD + dt * 128 + t]; }
  __syncthreads();
  {
    int q = t >> 1, half = t & 1;
    const float* src = qf + (size_t)(b * LQ + q) * DD + dt * 128 + half * 64;
    u16* dst = qw3_bf + (size_t)(b * LQ + q) * DD + dt * 128 + half * 64;
    float s2 = 0.f;
    #pragma unroll
    for (int j = 0; j < 8; ++j) {
      float4 a = *(const float4*)(src + j * 8);
      float4 c = *(const float4*)(src + j * 8 + 4);
      float vals[8] = {a.x, a.y, a.z, a.w, c.x, c.y, c.z, c.w};
      u16 u3[8] __attribute__((aligned(16)));
      #pragma unroll
      for (int jj = 0; jj < 8; ++jj) {
        int dl = half * 64 + j * 8 + jj;
        s2 += vals[jj] * w2s[dl];
        u3[jj] = f2bf(vals[jj] * w3s[dl]);
        ldsq[dl][q] = f2bf(vals[jj]);
      }
      *(short8*)(dst + j * 8) = *(short8*)u3;
    }
    s2 += __shfl_xor(s2, 1);
    if (half == 0) qwpart[(size_t)(b * 8 + dt) * LQ + q] = s2;
  }
  __syncthreads();
  {
    int d = t >> 1, qh = (t & 1) * 64;
    u16* gdst = qT_bf + (size_t)b * DD * LQ + (size_t)(dt * 128 + d) * LQ + qh;
    #pragma unroll
    for (int i = 0; i < 8; ++i) {
      short8 v = *(const short8*)(&ldsq[d][qh + i * 8]);
      *(short8*)(gdst + i * 8) = v;
    }
  }
}

// ---- kA phase-3 staging: async G->LDS with source-side swizzle ----
__device__ __forceinline__ void stage3(const u16* aqT, int dt,
                                       unsigned char* qbase, int wv, int lane) {
  #pragma unroll
  for (int i = 0; i < 4; ++i) {            // qT tile: 64 rows x 256B = 16KB
    unsigned rel = wv * 4096 + i * 1024 + lane * 16;
    int r = rel >> 8, c = (rel >> 4) & 15, cs = c ^ (r & 7);
    gld16(aqT + (size_t)(dt * 64 + r) * LQ + cs * 8, qbase + wv * 4096 + i * 1024);
  }
}

// ---------- kA: fused cvt + sim -> softmax -> c2q + q2c partials ----------
// cw = ctx . w1 now computed in F32 on the VALU alongside the A-tile staging
// (va[] already holds ctx in f32): removes the bf16 w1/accw MFMA path whose
// rounding error fed ONLY the q2c output (cw cancels in c2q's softmax over q).
// LDS overlay: psm (16KB, live ph2..ph3) aliases tile+32768 (dead half of the
// ph1 48KB dbuf; ph3 dbuf only uses tile[0,32768)). ~51.7KB -> 3 blocks/CU.
__global__ __launch_bounds__(256, 3) void kA(const float* __restrict__ ctx,
                                          const u16* __restrict__ qw3_bf,
                                          const u16* __restrict__ qT_bf,
                                          const float* __restrict__ w,
                                          const float* __restrict__ qwpart,
                                          float* __restrict__ c2q,
                                          float* __restrict__ partial,
                                          float* __restrict__ tileM,
                                          float* __restrict__ tileS) {
  __shared__ __align__(16) unsigned char tile[49152]; // ph1: 2 x (A8KB+B16KB); ph3: 2 x 16KB @ [0,32K)
  __shared__ float cws[CT];
  __shared__ float qws[LQ];
  __shared__ float rm2[2][CT];
  __shared__ float rs2[2][CT];
  __shared__ float rmax[CT];
  __shared__ float rinv[CT];
  __shared__ float wgtl[CT];

  unsigned char* psm = tile + 32768;      // P 64x128 bf16, live ph2..ph3

  const int tid = threadIdx.x;
  const int bid = blockIdx.x;
  // XCD-aware swizzle: 512 wgs, 8 XCDs -> XCD k owns logical blocks [k*64,(k+1)*64) = 4 whole batches
  const int blk = (bid & 7) * 64 + (bid >> 3);
  const int b   = blk >> 4;
  const int c0  = (blk & 15) * CT;
  const int lane = tid & 63;
  const int wv   = tid >> 6;
  const int wr   = wv >> 1;
  const int wc   = wv & 1;
  const int l15  = lane & 15;
  const int l4   = lane >> 4;

  if (tid < LQ) {
    float s = 0.f;
    #pragma unroll
    for (int dt = 0; dt < 8; ++dt) s += qwpart[(size_t)(b * 8 + dt) * LQ + tid];
    qws[tid] = s;
  }

  f4 acc[2][4];
  #pragma unroll
  for (int m = 0; m < 2; ++m)
    #pragma unroll
    for (int n = 0; n < 4; ++n) { f4 z = {0.f, 0.f, 0.f, 0.f}; acc[m][n] = z; }

  const float* actx = ctx + (size_t)(b * LC + c0) * DD;
  const u16* aq3  = qw3_bf + (size_t)b * LQ * DD;
  const u16* aqT  = qT_bf + (size_t)b * DD * LQ;

  const int ar  = tid >> 2;          // 0..63 : A-tile row
  const int akc = (tid & 3) * 16;    // k chunk within BK

  float va[16];
  float cwp = 0.f;                   // f32 partial of cw = ctx . w1 (this thread's k-slices)
  const float* w1p = w + akc;        // w1 = w[0..DD)

  // ---- phase 1: sim bilinear term; A: reg-staged fp32->bf16, B: gld16 ----
  { // prologue: tile 0
    const float* s = actx + (size_t)ar * DD + akc;
    *(float4*)(va)      = *(const float4*)(s);
    *(float4*)(va + 4)  = *(const float4*)(s + 4);
    *(float4*)(va + 8)  = *(const float4*)(s + 8);
    *(float4*)(va + 12) = *(const float4*)(s + 12);
    #pragma unroll
    for (int i = 0; i < 4; ++i) {
      unsigned rel = wv * 4096 + i * 1024 + lane * 16;
      int r = rel >> 7, c = (rel >> 4) & 7, cs = c ^ (r & 7);
      gld16(aq3 + (size_t)r * DD + cs * 8, tile + 8192 + wv * 4096 + i * 1024);
    }
    #pragma unroll
    for (int j = 0; j < 4; ++j) {    // f32 cw accumulation for tile 0 (k0_ = 0)
      float4 wv4 = *(const float4*)(w1p + j * 4);
      cwp += va[j * 4 + 0] * wv4.x + va[j * 4 + 1] * wv4.y +
             va[j * 4 + 2] * wv4.z + va[j * 4 + 3] * wv4.w;
    }
    u16 u[16] __attribute__((aligned(16)));
    #pragma unroll
    for (int j = 0; j < 16; ++j) u[j] = f2bf(va[j]);
    int cu = akc >> 3;
    *(short8*)(tile + ar * 128 + ((cu ^ (ar & 7)) << 4))       = *(short8*)u;
    *(short8*)(tile + ar * 128 + (((cu + 1) ^ (ar & 7)) << 4)) = *(short8*)(u + 8);
  }
  __syncthreads();

  for (int t = 0; t < 16; ++t) {
    int cur = t & 1;
    unsigned char* bufc = tile + cur * 24576;
    unsigned char* bufn = tile + (cur ^ 1) * 24576;
    if (t < 15) {
      int k0_ = (t + 1) * BK;
      const float* s = actx + (size_t)ar * DD + k0_ + akc;
      *(float4*)(va)      = *(const float4*)(s);
      *(float4*)(va + 4)  = *(const float4*)(s + 4);
      *(float4*)(va + 8)  = *(const float4*)(s + 8);
      *(float4*)(va + 12) = *(const float4*)(s + 12);
      #pragma unroll
      for (int i = 0; i < 4; ++i) {
        unsigned rel = wv * 4096 + i * 1024 + lane * 16;
        int r = rel >> 7, c = (rel >> 4) & 7, cs = c ^ (r & 7);
        gld16(aq3 + (size_t)r * DD + k0_ + cs * 8, bufn + 8192 + wv * 4096 + i * 1024);
      }
      #pragma unroll
      for (int j = 0; j < 4; ++j) {  // f32 cw accumulation for tile t+1
        float4 wv4 = *(const float4*)(w1p + k0_ + j * 4);
        cwp += va[j * 4 + 0] * wv4.x + va[j * 4 + 1] * wv4.y +
               va[j * 4 + 2] * wv4.z + va[j * 4 + 3] * wv4.w;
      }
    }
    #pragma unroll
    for (int kk = 0; kk < 2; ++kk) {
      short8 afr[2], bfr[4];
      #pragma unroll
      for (int m = 0; m < 2; ++m) {
        int r = wr * 32 + m * 16 + l15;
        int byte = r * 128 + kk * 64 + l4 * 16;
        byte ^= (r & 7) << 4;
        afr[m] = *(const short8*)(bufc + byte);
      }
      #pragma unroll
      for (int n = 0; n < 4; ++n) {
        int r = wc * 64 + n * 16 + l15;
        int byte = r * 128 + kk * 64 + l4 * 16;
        byte ^= (r & 7) << 4;
        bfr[n] = *(const short8*)(bufc + 8192 + byte);
      }
      #pragma unroll
      for (int m = 0; m < 2; ++m)
        #pragma unroll
        for (int n = 0; n < 4; ++n)
          acc[m][n] = __builtin_amdgcn_mfma_f32_16x16x32_bf16(afr[m], bfr[n], acc[m][n], 0, 0, 0);
    }
    if (t < 15) {
      u16 u[16] __attribute__((aligned(16)));
      #pragma unroll
      for (int j = 0; j < 16; ++j) u[j] = f2bf(va[j]);
      int cu = akc >> 3;
      *(short8*)(bufn + ar * 128 + ((cu ^ (ar & 7)) << 4))       = *(short8*)u;
      *(short8*)(bufn + ar * 128 + (((cu + 1) ^ (ar & 7)) << 4)) = *(short8*)(u + 8);
    }
    __syncthreads();
  }

  // ---- cw finalize: quad-reduce (lanes 4k..4k+3 share row ar) and write f32-exact cws ----
  cwp += __shfl_xor(cwp, 1);
  cwp += __shfl_xor(cwp, 2);
  if ((lane & 3) == 0) cws[ar] = cwp;
  __syncthreads();

  // ---- phase 2: add cw+qw, rowmax, exp, rowsum, write P ----
  #pragma unroll
  for (int m = 0; m < 2; ++m) {
    #pragma unroll
    for (int j = 0; j < 4; ++j) {
      int cl = wr * 32 + m * 16 + l4 * 4 + j;
      float mx = -1e30f;
      #pragma unroll
      for (int n = 0; n < 4; ++n) {
        float v = acc[m][n][j] + cws[cl] + qws[wc * 64 + n * 16 + l15];
        acc[m][n][j] = v;
        mx = fmaxf(mx, v);
      }
      #pragma unroll
      for (int off = 1; off < 16; off <<= 1) mx = fmaxf(mx, __shfl_xor(mx, off));
      if (l15 == 0) rm2[wc][cl] = mx;
    }
  }
  __syncthreads();
  if (tid < CT) rmax[tid] = fmaxf(rm2[0][tid], rm2[1][tid]);
  __syncthreads();
  #pragma unroll
  for (int m = 0; m < 2; ++m) {
    #pragma unroll
    for (int j = 0; j < 4; ++j) {
      int cl = wr * 32 + m * 16 + l4 * 4 + j;
      float mx = rmax[cl];
      float s = 0.f;
      #pragma unroll
      for (int n = 0; n < 4; ++n) {
        float p = __expf(acc[m][n][j] - mx);
        s += p;
        int q = wc * 64 + n * 16 + l15;
        int byte = cl * (LQ * 2) + q * 2;
        byte ^= (cl & 7) << 4;
        *(u16*)(psm + byte) = f2bf(p);
      }
      #pragma unroll
      for (int off = 1; off < 16; off <<= 1) s += __shfl_xor(s, off);
      if (l15 == 0) rs2[wc][cl] = s;
    }
  }
  __syncthreads();
  if (tid < CT) {   // wave 0: rinv + tile softmax stats for q2c
    rinv[tid] = 1.f / (rs2[0][tid] + rs2[1][tid]);
    float m = rmax[tid];
    float M = m;
    #pragma unroll
    for (int off = 32; off; off >>= 1) M = fmaxf(M, __shfl_xor(M, off));
    float wq = __expf(m - M);
    wgtl[tid] = wq;
    float S = wq;
    #pragma unroll
    for (int off = 32; off; off >>= 1) S += __shfl_xor(S, off);
    if (tid == 0) { tileM[blk] = M; tileS[blk] = S; }
  }
  __syncthreads();

  // phase-3 prologue staging (barrier required: dt=0 reads tile[0,16K))
  stage3(aqT, 0, tile, wv, lane);
  __syncthreads();

  float ri[2];
  ri[0] = rinv[wr * 32 + l15];
  ri[1] = rinv[wr * 32 + 16 + l15];

  // q2c tile-partial accumulator (phase 2.5 interleaved into the dt loop)
  f4 pacc25 = {0.f, 0.f, 0.f, 0.f};
  const float* pbase = actx + tid * 4;

  // ---- phase 3: c2q = P @ q (swapped MFMA -> [d][c] frags, float4 stores) ----
  for (int dt = 0; dt < 16; ++dt) {
    int cur = dt & 1;
    if (dt < 15) stage3(aqT, dt + 1, tile + (cur ^ 1) * 16384, wv, lane);
    // interleaved phase 2.5: 4 c-rows of the wgt GEMV per dt iteration (cache reads hide under MFMA)
    #pragma unroll
    for (int cc = 0; cc < 4; ++cc) {
      int c = dt * 4 + cc;
      pacc25 += wgtl[c] * *(const f4*)(pbase + (size_t)c * DD);
    }
    unsigned char* qbase = tile + cur * 16384;
    f4 pacc[2][2];  // [n][m]
    #pragma unroll
    for (int n = 0; n < 2; ++n)
      #pragma unroll
      for (int m = 0; m < 2; ++m) { f4 z = {0.f, 0.f, 0.f, 0.f}; pacc[n][m] = z; }
    #pragma unroll
    for (int kk = 0; kk < 4; ++kk) {
      short8 pa[2], qb[2];
      #pragma unroll
      for (int m = 0; m < 2; ++m) {
        int r = wr * 32 + m * 16 + l15;
        int byte = r * 256 + kk * 64 + l4 * 16;
        byte ^= (r & 7) << 4;
        pa[m] = *(const short8*)(psm + byte);
      }
      #pragma unroll
      for (int n = 0; n < 2; ++n) {
        int dl = wc * 32 + n * 16 + l15;
        int byte = dl * 256 + kk * 64 + l4 * 16;
        byte ^= (dl & 7) << 4;
        qb[n] = *(const short8*)(qbase + byte);
      }
      #pragma unroll
      for (int n = 0; n < 2; ++n)
        #pragma unroll
        for (int m = 0; m < 2; ++m)
          pacc[n][m] = __builtin_amdgcn_mfma_f32_16x16x32_bf16(qb[n], pa[m], pacc[n][m], 0, 0, 0);
    }
    #pragma unroll
    for (int n = 0; n < 2; ++n)
      #pragma unroll
      for (int m = 0; m < 2; ++m) {
        f4 v = pacc[n][m] * ri[m];
        int cl = wr * 32 + m * 16 + l15;
        int dc = wc * 32 + n * 16 + l4 * 4;
        *(f4*)(c2q + (size_t)(b * LC + c0 + cl) * DD + dt * 64 + dc) = v;
      }
    __syncthreads();
  }

  // phase 2.5 epilogue: store q2c tile-partial
  *(f4*)(partial + (size_t)blk * DD + tid * 4) = pacc25;
}

// ---------- kQC2: combine tile partials + broadcast q2c to (B, Lc, D) ----------
__global__ __launch_bounds__(256) void kQC2(const float* __restrict__ partial,
                                            const float* __restrict__ tileM,
                                            const float* __restrict__ tileS,
                                            float* __restrict__ out2) {
  int blk = blockIdx.x;            // 32 b * 32 row-chunks
  int b = blk >> 5, cb = blk & 31;
  int t = threadIdx.x;
  __shared__ float sc[16];
  __shared__ float dninv;
  if (t < 16) {
    float m = tileM[b * 16 + t];
    float M = m;
    #pragma unroll
    for (int off = 8; off; off >>= 1) M = fmaxf(M, __shfl_xor(M, off));
    float e = __expf(m - M);
    sc[t] = e;
    float d = e * tileS[b * 16 + t];
    #pragma unroll
    for (int off = 8; off; off >>= 1) d += __shfl_xor(d, off);
    if (t == 0) dninv = 1.f / d;
  }
  __syncthreads();
  f4 a = {0.f, 0.f, 0.f, 0.f};
  #pragma unroll
  for (int i = 0; i < 16; ++i) {
    float s = sc[i];
    f4 v = *(const f4*)(partial + (size_t)(b * 16 + i) * DD + t * 4);
    a += s * v;
  }
  a *= dninv;
  float* dst = out2 + ((size_t)b * LC + cb * 32) * DD + t * 4;
  #pragma unroll
  for (int r = 0; r < 32; ++r) *(f4*)(dst + (size_t)r * DD) = a;
}

extern "C" void kernel_launch(void* const* d_in, const int* in_sizes, int n_in,
                              void* d_out, int out_size, void* d_ws, size_t ws_size,
                              hipStream_t stream) {
  (void)in_sizes; (void)n_in; (void)out_size; (void)ws_size;
  const float* ctx = (const float*)d_in[0];
  const float* qf  = (const float*)d_in[1];
  const float* w   = (const float*)d_in[2];
  float* out      = (float*)d_out;
  float* c2q      = out;
  float* q2c_out  = out + (size_t)B_ * LC * DD;

  float* ws     = (float*)d_ws;
  float* qwpart = ws;                          // 32*8*128 = 32768
  float* tileM  = qwpart + B_ * 8 * LQ;        // 512
  float* tileS  = tileM + 512;                 // 512
  float* part   = tileS + 512;                 // 512*1024
  u16*   qw3_bf = (u16*)(part + 512 * DD);     // 8MB
  u16*   qT_bf  = qw3_bf + (size_t)B_ * LQ * DD;

  hipLaunchKernelGGL(k1m,  dim3(256),  dim3(256), 0, stream, qf, w, qw3_bf, qT_bf, qwpart);
  hipLaunchKernelGGL(kA,   dim3(512),  dim3(256), 0, stream, ctx, qw3_bf, qT_bf, w, qwpart, c2q, part, tileM, tileS);
  hipLaunchKernelGGL(kQC2, dim3(1024), dim3(256), 0, stream, part, tileM, tileS, q2c_out);
}

// Round 4
// 136.419 us; speedup vs baseline: 1.0083x; 1.0083x over previous
//
#include <hip/hip_runtime.h>
#include <hip/hip_bf16.h>
#include <stdint.h>

#define B_  32
#define LC  1024
#define LQ  128
#define DD  1024
#define CT  64
#define BK  64

typedef __attribute__((ext_vector_type(8))) short short8;
typedef __attribute__((ext_vector_type(4))) float f4;
typedef unsigned short u16;

__device__ __forceinline__ u16 f2bf(float f) {
  __hip_bfloat16 h = __float2bfloat16(f);
  return *reinterpret_cast<u16*>(&h);
}

// async global->LDS 16B per lane; lds ptr wave-uniform (HW adds lane*16)
__device__ __forceinline__ void gld16(const u16* g, void* l) {
  __builtin_amdgcn_global_load_lds(
      (const __attribute__((address_space(1))) unsigned int*)g,
      (__attribute__((address_space(3))) unsigned int*)l,
      16, 0, 0);
}

// counted-vmcnt barrier (T4): retires this iteration's 4 gld16 (older) and all
// DS ops, leaves the 4 newest vmem ops (the deep ctx prefetch) in flight.
__device__ __forceinline__ void barrier_vm4() {
  __builtin_amdgcn_sched_barrier(0);
  asm volatile("s_waitcnt vmcnt(4) lgkmcnt(0)" ::: "memory");
  __builtin_amdgcn_s_barrier();
  __builtin_amdgcn_sched_barrier(0);
}

// ---------- k1m: q prep — qw3_bf [b][q][d], qT_bf [b][d][q], qw partials ----------
__global__ __launch_bounds__(256) void k1m(const float* __restrict__ qf,
                                           const float* __restrict__ w,
                                           u16* __restrict__ qw3_bf,
                                           u16* __restrict__ qT_bf,
                                           float* __restrict__ qwpart) {
  __shared__ float w3s[128];
  __shared__ float w2s[128];
  __shared__ __align__(16) u16 ldsq[128][136];
  int blk = blockIdx.x;
  int b = blk >> 3, dt = blk & 7;
  int t = threadIdx.x;
  if (t < 128) { w3s[t] = w[2 * DD + dt * 128 + t]; w2s[t] = w[DD + dt * 128 + t]; }
  __syncthreads();
  {
    int q = t >> 1, half = t & 1;
    const float* src = qf + (size_t)(b * LQ + q) * DD + dt * 128 + half * 64;
    u16* dst = qw3_bf + (size_t)(b * LQ + q) * DD + dt * 128 + half * 64;
    float s2 = 0.f;
    #pragma unroll
    for (int j = 0; j < 8; ++j) {
      float4 a = *(const float4*)(src + j * 8);
      float4 c = *(const float4*)(src + j * 8 + 4);
      float vals[8] = {a.x, a.y, a.z, a.w, c.x, c.y, c.z, c.w};
      u16 u3[8] __attribute__((aligned(16)));
      #pragma unroll
      for (int jj = 0; jj < 8; ++jj) {
        int dl = half * 64 + j * 8 + jj;
        s2 += vals[jj] * w2s[dl];
        u3[jj] = f2bf(vals[jj] * w3s[dl]);
        ldsq[dl][q] = f2bf(vals[jj]);
      }
      *(short8*)(dst + j * 8) = *(short8*)u3;
    }
    s2 += __shfl_xor(s2, 1);
    if (half == 0) qwpart[(size_t)(b * 8 + dt) * LQ + q] = s2;
  }
  __syncthreads();
  {
    int d = t >> 1, qh = (t & 1) * 64;
    u16* gdst = qT_bf + (size_t)b * DD * LQ + (size_t)(dt * 128 + d) * LQ + qh;
    #pragma unroll
    for (int i = 0; i < 8; ++i) {
      short8 v = *(const short8*)(&ldsq[d][qh + i * 8]);
      *(short8*)(gdst + i * 8) = v;
    }
  }
}

// ---- kA phase-3 staging: async G->LDS with source-side swizzle ----
__device__ __forceinline__ void stage3(const u16* aqT, int dt,
                                       unsigned char* qbase, int wv, int lane) {
  #pragma unroll
  for (int i = 0; i < 4; ++i) {            // qT tile: 64 rows x 256B = 16KB
    unsigned rel = wv * 4096 + i * 1024 + lane * 16;
    int r = rel >> 8, c = (rel >> 4) & 15, cs = c ^ (r & 7);
    gld16(aqT + (size_t)(dt * 64 + r) * LQ + cs * 8, qbase + wv * 4096 + i * 1024);
  }
}

// ---- phase-1 building blocks (macros: everything stays in registers) ----
#define STAGEB_PH1(K0, BUF)                                                    \
  do {                                                                         \
    _Pragma("unroll")                                                          \
    for (int i_ = 0; i_ < 4; ++i_) {                                           \
      unsigned rel_ = wv * 4096 + i_ * 1024 + lane * 16;                       \
      int r_ = rel_ >> 7, c_ = (rel_ >> 4) & 7, cs_ = c_ ^ (r_ & 7);           \
      gld16(aq3 + (size_t)r_ * DD + (K0) + cs_ * 8,                            \
            (BUF) + 8192 + wv * 4096 + i_ * 1024);                             \
    }                                                                          \
  } while (0)

#define LOADCTX_PH1(VA, K0)                                                    \
  do {                                                                         \
    const float* s_ = actx + (size_t)ar * DD + (K0) + akc;                     \
    *(float4*)(VA)      = *(const float4*)(s_);                                \
    *(float4*)(VA + 4)  = *(const float4*)(s_ + 4);                            \
    *(float4*)(VA + 8)  = *(const float4*)(s_ + 8);                            \
    *(float4*)(VA + 12) = *(const float4*)(s_ + 12);                           \
  } while (0)

#define CWWRITE_PH1(VA, K0, BUF)                                               \
  do {                                                                         \
    _Pragma("unroll")                                                          \
    for (int j_ = 0; j_ < 4; ++j_) {                                           \
      float4 w4_ = *(const float4*)(&w1s[(K0) + akc + j_ * 4]);                \
      cwp += (VA)[j_ * 4 + 0] * w4_.x + (VA)[j_ * 4 + 1] * w4_.y +             \
             (VA)[j_ * 4 + 2] * w4_.z + (VA)[j_ * 4 + 3] * w4_.w;              \
    }                                                                          \
    {                                                                          \
      u16 u_[16] __attribute__((aligned(16)));                                 \
      _Pragma("unroll")                                                        \
      for (int j_ = 0; j_ < 16; ++j_) u_[j_] = f2bf((VA)[j_]);                 \
      int cu_ = akc >> 3;                                                      \
      *(short8*)((BUF) + ar * 128 + ((cu_ ^ (ar & 7)) << 4)) = *(short8*)u_;   \
      *(short8*)((BUF) + ar * 128 + (((cu_ + 1) ^ (ar & 7)) << 4)) =           \
          *(short8*)(u_ + 8);                                                  \
    }                                                                          \
  } while (0)

#define MFMA_PH1(BUFC)                                                         \
  do {                                                                         \
    _Pragma("unroll")                                                          \
    for (int kk = 0; kk < 2; ++kk) {                                           \
      short8 afr[2], bfr[4];                                                   \
      _Pragma("unroll")                                                        \
      for (int m_ = 0; m_ < 2; ++m_) {                                         \
        int r_ = wr * 32 + m_ * 16 + l15;                                      \
        int byte_ = r_ * 128 + kk * 64 + l4 * 16;                              \
        byte_ ^= (r_ & 7) << 4;                                                \
        afr[m_] = *(const short8*)((BUFC) + byte_);                            \
      }                                                                        \
      _Pragma("unroll")                                                        \
      for (int n_ = 0; n_ < 4; ++n_) {                                         \
        int r_ = wc * 64 + n_ * 16 + l15;                                      \
        int byte_ = r_ * 128 + kk * 64 + l4 * 16;                              \
        byte_ ^= (r_ & 7) << 4;                                                \
        bfr[n_] = *(const short8*)((BUFC) + 8192 + byte_);                     \
      }                                                                        \
      _Pragma("unroll")                                                        \
      for (int m_ = 0; m_ < 2; ++m_)                                           \
        _Pragma("unroll")                                                      \
        for (int n_ = 0; n_ < 4; ++n_)                                         \
          acc[m_][n_] = __builtin_amdgcn_mfma_f32_16x16x32_bf16(               \
              afr[m_], bfr[n_], acc[m_][n_], 0, 0, 0);                         \
    }                                                                          \
  } while (0)

// One deep-pipelined phase-1 iteration T. VA_WR holds ctx tile T+1 (written to
// LDS now); VA_LD receives ctx tile T+2 (issued NEWEST, rides across barrier).
// Per-wave vmem order pinned: [gld16 B(T+1) x4][ctx(T+2) x4].
#define PH1_ITER(T, VA_WR, VA_LD, BUFC, BUFN)                                  \
  do {                                                                         \
    STAGEB_PH1(((T) + 1) * BK, BUFN);                                          \
    __builtin_amdgcn_sched_barrier(0);                                         \
    LOADCTX_PH1(VA_LD, ((T) + 2) * BK);                                        \
    MFMA_PH1(BUFC);                                                            \
    CWWRITE_PH1(VA_WR, ((T) + 1) * BK, BUFN);                                  \
    barrier_vm4();                                                             \
  } while (0)

// ---------- kA: fused cvt + sim -> softmax -> c2q + q2c partials ----------
// Phase 1 is deep-pipelined (depth-2 ctx prefetch + counted-vmcnt barriers):
// the ctx HBM loads for tile T+2 stay in flight ACROSS the barrier (T4), giving
// them ~1.5 iterations to complete instead of the MFMA phase only. w1 lives in
// f32 LDS so the cw GEMV is lgkm-only (a global w1 read at the iteration
// bottom would force an in-order vmcnt drain of the prefetch).
// LDS overlay: psm (16KB) aliases tile+32768 (dead half of ph1 dbuf).
__global__ __launch_bounds__(256, 2) void kA(const float* __restrict__ ctx,
                                          const u16* __restrict__ qw3_bf,
                                          const u16* __restrict__ qT_bf,
                                          const float* __restrict__ w,
                                          const float* __restrict__ qwpart,
                                          float* __restrict__ c2q,
                                          float* __restrict__ partial,
                                          float* __restrict__ tileM,
                                          float* __restrict__ tileS) {
  __shared__ __align__(16) unsigned char tile[49152]; // ph1: 2 x (A8KB+B16KB); ph3: 2 x 16KB @ [0,32K)
  __shared__ __align__(16) float w1s[DD];             // f32 w1 (ph1 cw GEMV, lgkm-only)
  __shared__ float cws[CT];
  __shared__ float qws[LQ];
  __shared__ float rm2[2][CT];
  __shared__ float rs2[2][CT];
  __shared__ float rmax[CT];
  __shared__ float rinv[CT];
  __shared__ float wgtl[CT];

  unsigned char* psm = tile + 32768;      // P 64x128 bf16, live ph2..ph3

  const int tid = threadIdx.x;
  const int bid = blockIdx.x;
  // XCD-aware swizzle: 512 wgs, 8 XCDs -> XCD k owns logical blocks [k*64,(k+1)*64) = 4 whole batches
  const int blk = (bid & 7) * 64 + (bid >> 3);
  const int b   = blk >> 4;
  const int c0  = (blk & 15) * CT;
  const int lane = tid & 63;
  const int wv   = tid >> 6;
  const int wr   = wv >> 1;
  const int wc   = wv & 1;
  const int l15  = lane & 15;
  const int l4   = lane >> 4;

  *(f4*)(&w1s[tid * 4]) = *(const f4*)(w + tid * 4);   // 256 threads x 16B = 4KB
  if (tid < LQ) {
    float s = 0.f;
    #pragma unroll
    for (int dt = 0; dt < 8; ++dt) s += qwpart[(size_t)(b * 8 + dt) * LQ + tid];
    qws[tid] = s;
  }

  f4 acc[2][4];
  #pragma unroll
  for (int m = 0; m < 2; ++m)
    #pragma unroll
    for (int n = 0; n < 4; ++n) { f4 z = {0.f, 0.f, 0.f, 0.f}; acc[m][n] = z; }

  const float* actx = ctx + (size_t)(b * LC + c0) * DD;
  const u16* aq3  = qw3_bf + (size_t)b * LQ * DD;
  const u16* aqT  = qT_bf + (size_t)b * DD * LQ;

  const int ar  = tid >> 2;          // 0..63 : A-tile row
  const int akc = (tid & 3) * 16;    // k chunk within BK

  float vaA[16], vaB[16];
  float cwp = 0.f;                   // f32 partial of cw = ctx . w1

  __syncthreads();                   // w1s / qws visible

  // ---- phase 1 prologue: tile0 -> vaA -> LDS; tile1 -> vaB (in flight) ----
  {
    LOADCTX_PH1(vaA, 0);
    __builtin_amdgcn_sched_barrier(0);
    STAGEB_PH1(0, tile);
    __builtin_amdgcn_sched_barrier(0);
    CWWRITE_PH1(vaA, 0, tile);       // auto-waits ctx0 only (gld16 B0 newer)
    LOADCTX_PH1(vaB, BK);            // newest: rides across the barrier
    barrier_vm4();                   // retires gld16 B0; ctx1 in flight
  }

  // ---- phase 1 main: t = 0..13 deep-pipelined ----
  for (int t2 = 0; t2 < 7; ++t2) {
    PH1_ITER(2 * t2,     vaB, vaA, tile,         tile + 24576);
    PH1_ITER(2 * t2 + 1, vaA, vaB, tile + 24576, tile);
  }
  // t=14: stage B tile15, write A tile15 (vaB); no deeper load -> full drain
  {
    STAGEB_PH1(15 * BK, tile + 24576);
    MFMA_PH1(tile);
    CWWRITE_PH1(vaB, 15 * BK, tile + 24576);
    __syncthreads();
  }
  // t=15: compute only
  MFMA_PH1(tile + 24576);
  __syncthreads();

  // ---- cw finalize: quad-reduce (lanes 4k..4k+3 share row ar) and write f32-exact cws ----
  cwp += __shfl_xor(cwp, 1);
  cwp += __shfl_xor(cwp, 2);
  if ((lane & 3) == 0) cws[ar] = cwp;
  __syncthreads();

  // ---- phase 2: add cw+qw, rowmax, exp, rowsum, write P ----
  #pragma unroll
  for (int m = 0; m < 2; ++m) {
    #pragma unroll
    for (int j = 0; j < 4; ++j) {
      int cl = wr * 32 + m * 16 + l4 * 4 + j;
      float mx = -1e30f;
      #pragma unroll
      for (int n = 0; n < 4; ++n) {
        float v = acc[m][n][j] + cws[cl] + qws[wc * 64 + n * 16 + l15];
        acc[m][n][j] = v;
        mx = fmaxf(mx, v);
      }
      #pragma unroll
      for (int off = 1; off < 16; off <<= 1) mx = fmaxf(mx, __shfl_xor(mx, off));
      if (l15 == 0) rm2[wc][cl] = mx;
    }
  }
  __syncthreads();
  if (tid < CT) rmax[tid] = fmaxf(rm2[0][tid], rm2[1][tid]);
  __syncthreads();
  #pragma unroll
  for (int m = 0; m < 2; ++m) {
    #pragma unroll
    for (int j = 0; j < 4; ++j) {
      int cl = wr * 32 + m * 16 + l4 * 4 + j;
      float mx = rmax[cl];
      float s = 0.f;
      #pragma unroll
      for (int n = 0; n < 4; ++n) {
        float p = __expf(acc[m][n][j] - mx);
        s += p;
        int q = wc * 64 + n * 16 + l15;
        int byte = cl * (LQ * 2) + q * 2;
        byte ^= (cl & 7) << 4;
        *(u16*)(psm + byte) = f2bf(p);
      }
      #pragma unroll
      for (int off = 1; off < 16; off <<= 1) s += __shfl_xor(s, off);
      if (l15 == 0) rs2[wc][cl] = s;
    }
  }
  __syncthreads();
  if (tid < CT) {   // wave 0: rinv + tile softmax stats for q2c
    rinv[tid] = 1.f / (rs2[0][tid] + rs2[1][tid]);
    float m = rmax[tid];
    float M = m;
    #pragma unroll
    for (int off = 32; off; off >>= 1) M = fmaxf(M, __shfl_xor(M, off));
    float wq = __expf(m - M);
    wgtl[tid] = wq;
    float S = wq;
    #pragma unroll
    for (int off = 32; off; off >>= 1) S += __shfl_xor(S, off);
    if (tid == 0) { tileM[blk] = M; tileS[blk] = S; }
  }
  __syncthreads();

  // phase-3 prologue staging (barrier required: dt=0 reads tile[0,16K))
  stage3(aqT, 0, tile, wv, lane);
  __syncthreads();

  float ri[2];
  ri[0] = rinv[wr * 32 + l15];
  ri[1] = rinv[wr * 32 + 16 + l15];

  // q2c tile-partial accumulator (phase 2.5 interleaved into the dt loop)
  f4 pacc25 = {0.f, 0.f, 0.f, 0.f};
  const float* pbase = actx + tid * 4;

  // ---- phase 3: c2q = P @ q (swapped MFMA -> [d][c] frags, float4 stores) ----
  for (int dt = 0; dt < 16; ++dt) {
    int cur = dt & 1;
    if (dt < 15) stage3(aqT, dt + 1, tile + (cur ^ 1) * 16384, wv, lane);
    // interleaved phase 2.5: 4 c-rows of the wgt GEMV per dt iteration (cache reads hide under MFMA)
    #pragma unroll
    for (int cc = 0; cc < 4; ++cc) {
      int c = dt * 4 + cc;
      pacc25 += wgtl[c] * *(const f4*)(pbase + (size_t)c * DD);
    }
    unsigned char* qbase = tile + cur * 16384;
    f4 pacc[2][2];  // [n][m]
    #pragma unroll
    for (int n = 0; n < 2; ++n)
      #pragma unroll
      for (int m = 0; m < 2; ++m) { f4 z = {0.f, 0.f, 0.f, 0.f}; pacc[n][m] = z; }
    #pragma unroll
    for (int kk = 0; kk < 4; ++kk) {
      short8 pa[2], qb[2];
      #pragma unroll
      for (int m = 0; m < 2; ++m) {
        int r = wr * 32 + m * 16 + l15;
        int byte = r * 256 + kk * 64 + l4 * 16;
        byte ^= (r & 7) << 4;
        pa[m] = *(const short8*)(psm + byte);
      }
      #pragma unroll
      for (int n = 0; n < 2; ++n) {
        int dl = wc * 32 + n * 16 + l15;
        int byte = dl * 256 + kk * 64 + l4 * 16;
        byte ^= (dl & 7) << 4;
        qb[n] = *(const short8*)(qbase + byte);
      }
      #pragma unroll
      for (int n = 0; n < 2; ++n)
        #pragma unroll
        for (int m = 0; m < 2; ++m)
          pacc[n][m] = __builtin_amdgcn_mfma_f32_16x16x32_bf16(qb[n], pa[m], pacc[n][m], 0, 0, 0);
    }
    #pragma unroll
    for (int n = 0; n < 2; ++n)
      #pragma unroll
      for (int m = 0; m < 2; ++m) {
        f4 v = pacc[n][m] * ri[m];
        int cl = wr * 32 + m * 16 + l15;
        int dc = wc * 32 + n * 16 + l4 * 4;
        *(f4*)(c2q + (size_t)(b * LC + c0 + cl) * DD + dt * 64 + dc) = v;
      }
    __syncthreads();
  }

  // phase 2.5 epilogue: store q2c tile-partial
  *(f4*)(partial + (size_t)blk * DD + tid * 4) = pacc25;
}

// ---------- kQC2: combine tile partials + broadcast q2c to (B, Lc, D) ----------
__global__ __launch_bounds__(256) void kQC2(const float* __restrict__ partial,
                                            const float* __restrict__ tileM,
                                            const float* __restrict__ tileS,
                                            float* __restrict__ out2) {
  int blk = blockIdx.x;            // 32 b * 32 row-chunks
  int b = blk >> 5, cb = blk & 31;
  int t = threadIdx.x;
  __shared__ float sc[16];
  __shared__ float dninv;
  if (t < 16) {
    float m = tileM[b * 16 + t];
    float M = m;
    #pragma unroll
    for (int off = 8; off; off >>= 1) M = fmaxf(M, __shfl_xor(M, off));
    float e = __expf(m - M);
    sc[t] = e;
    float d = e * tileS[b * 16 + t];
    #pragma unroll
    for (int off = 8; off; off >>= 1) d += __shfl_xor(d, off);
    if (t == 0) dninv = 1.f / d;
  }
  __syncthreads();
  f4 a = {0.f, 0.f, 0.f, 0.f};
  #pragma unroll
  for (int i = 0; i < 16; ++i) {
    float s = sc[i];
    f4 v = *(const f4*)(partial + (size_t)(b * 16 + i) * DD + t * 4);
    a += s * v;
  }
  a *= dninv;
  float* dst = out2 + ((size_t)b * LC + cb * 32) * DD + t * 4;
  #pragma unroll
  for (int r = 0; r < 32; ++r) *(f4*)(dst + (size_t)r * DD) = a;
}

extern "C" void kernel_launch(void* const* d_in, const int* in_sizes, int n_in,
                              void* d_out, int out_size, void* d_ws, size_t ws_size,
                              hipStream_t stream) {
  (void)in_sizes; (void)n_in; (void)out_size; (void)ws_size;
  const float* ctx = (const float*)d_in[0];
  const float* qf  = (const float*)d_in[1];
  const float* w   = (const float*)d_in[2];
  float* out      = (float*)d_out;
  float* c2q      = out;
  float* q2c_out  = out + (size_t)B_ * LC * DD;

  float* ws     = (float*)d_ws;
  float* qwpart = ws;                          // 32*8*128 = 32768
  float* tileM  = qwpart + B_ * 8 * LQ;        // 512
  float* tileS  = tileM + 512;                 // 512
  float* part   = tileS + 512;                 // 512*1024
  u16*   qw3_bf = (u16*)(part + 512 * DD);     // 8MB
  u16*   qT_bf  = qw3_bf + (size_t)B_ * LQ * DD;

  hipLaunchKernelGGL(k1m,  dim3(256),  dim3(256), 0, stream, qf, w, qw3_bf, qT_bf, qwpart);
  hipLaunchKernelGGL(kA,   dim3(512),  dim3(256), 0, stream, ctx, qw3_bf, qT_bf, w, qwpart, c2q, part, tileM, tileS);
  hipLaunchKernelGGL(kQC2, dim3(1024), dim3(256), 0, stream, part, tileM, tileS, q2c_out);
}